// Round 6
// baseline (119.750 us; speedup 1.0000x reference)
//
#include <hip/hip_runtime.h>

// SecurePooling: x (32,1000,14,14) f32 -> pred (32,) int32
// Even-coordinate SAT S[r][c] = sum(x[0:2r,0:2c]), r,c in 0..7 is a complete
// sufficient statistic. 351 streams per b: 325 unordered pairs (two[p][q]),
// 25 one-mask, 1 total.  Argmax over c per stream, first-index tie-break.
// kernB: thread=(b,c), S in registers, all 351 streams unrolled per wave,
// wave(64 c's) DPP-max reduce + ballot -> per-chunk partial keys.

#define NC 1000
#define NBC 32000   // 32*1000
#define NCH 16      // c-chunks of 64 (chunk 15 overlaps: c0=936)
#define PSTRIDE 384

__host__ __device__ constexpr int tri_off(int p) { return p * 25 - p * (p - 1) / 2; }

// ---------------- Kernel A: per-(b,c) even SAT, LDS-staged coalesced ----------------
__global__ __launch_bounds__(256) void satA(const float* __restrict__ x,
                                            float* __restrict__ Sws) {
    __shared__ float lx[64 * 197];                       // odd stride: conflict-free
    const int tid = threadIdx.x;
    const int blk = blockIdx.x;                          // 500 blocks x 64 images
    const float4* x4 = reinterpret_cast<const float4*>(x) + (size_t)blk * 3136;
#pragma unroll
    for (int it = 0; it < 13; ++it) {
        int f = it * 256 + tid;                          // 3136 float4 per block
        if (f < 3136) {
            float4 v = x4[f];
            int img = f / 49;
            int off = f - img * 49;
            float* d = &lx[img * 197 + off * 4];
            d[0] = v.x; d[1] = v.y; d[2] = v.z; d[3] = v.w;
        }
    }
    __syncthreads();
    if (tid < 64) {
        const float* im = &lx[tid * 197];
        float S[8][8];
#pragma unroll
        for (int c = 0; c < 8; ++c) S[0][c] = 0.f;
        float colacc[7];
#pragma unroll
        for (int c = 0; c < 7; ++c) colacc[c] = 0.f;
#pragma unroll
        for (int r = 0; r < 7; ++r) {
            float rowf[28];
#pragma unroll
            for (int j = 0; j < 28; ++j) rowf[j] = im[r * 28 + j];
            S[r + 1][0] = 0.f;
            float run = 0.f;
#pragma unroll
            for (int c = 0; c < 7; ++c) {
                float blk2 = rowf[2 * c] + rowf[2 * c + 1] + rowf[14 + 2 * c] + rowf[14 + 2 * c + 1];
                colacc[c] += blk2;
                run += colacc[c];
                S[r + 1][c + 1] = run;
            }
        }
        const int bc = blk * 64 + tid;
#pragma unroll
        for (int k = 0; k < 64; ++k)
            Sws[(size_t)k * NBC + bc] = S[k >> 3][k & 7];
    }
}

// ---------------- Kernel B: register-resident streams, DPP wave argmax ----------------
template <int CTRL>
__device__ __forceinline__ float dppmax(float v) {
    int o = __builtin_amdgcn_update_dpp(__float_as_int(v), __float_as_int(v),
                                        CTRL, 0xF, 0xF, false);
    return fmaxf(v, __int_as_float(o));
}

__global__ __launch_bounds__(128) void kernB(const float* __restrict__ Sws,
                                             unsigned long long* __restrict__ part) {
    const int tid = threadIdx.x;
    const int lane = tid & 63;
    const int b = blockIdx.x >> 3;
    const int wc = ((blockIdx.x & 7) << 1) + (tid >> 6);   // 0..15
    const int c0 = (wc == 15) ? 936 : wc * 64;             // chunk 15 overlaps 14
    const int c = c0 + lane;

    float S[64];
#pragma unroll
    for (int k = 0; k < 64; ++k)
        S[k] = Sws[(size_t)k * NBC + b * NC + c];
    const float total = S[63];

    // window sums + one-mask logits (same FP order as verified R2 kernel)
    float w_[25], lt[25];
#pragma unroll
    for (int p1 = 0; p1 < 5; ++p1)
#pragma unroll
        for (int p2 = 0; p2 < 5; ++p2) {
            float ww = ((S[(p1 + 3) * 8 + (p2 + 3)] - S[p1 * 8 + (p2 + 3)])
                        - S[(p1 + 3) * 8 + p2]) + S[p1 * 8 + p2];
            w_[p1 * 5 + p2] = ww;
            lt[p1 * 5 + p2] = total - ww;
        }

    int rs_lo[6], rs_hi[6];
#pragma unroll
    for (int j = 0; j < 6; ++j) { rs_lo[j] = 0; rs_hi[j] = 0; }

    // Per-stream wave argmax; packed result is wave-uniform, deposited into
    // lane (SID&63)'s rs_{lo,hi}[SID>>6] via predicated assignment
    // (writelane equivalent; SID is compile-time so indexing stays static).
    // DPP chain: row_shr 1,2,4,8 then row_bcast15, row_bcast31 -> lane63 has max.
#define EMIT(VAL, SID)                                                          \
    {                                                                           \
        float _v = (VAL);                                                       \
        float _m = _v;                                                          \
        _m = dppmax<0x111>(_m); _m = dppmax<0x112>(_m);                         \
        _m = dppmax<0x114>(_m); _m = dppmax<0x118>(_m);                         \
        _m = dppmax<0x142>(_m); _m = dppmax<0x143>(_m);                         \
        int _mb = __builtin_amdgcn_readlane(__float_as_int(_m), 63);            \
        unsigned long long _eq = __ballot(__float_as_int(_v) == _mb);           \
        int _off = __ffsll(_eq) - 1;                                            \
        unsigned _cw = (unsigned)(c0 + _off);                                   \
        unsigned _u = (unsigned)_mb;                                            \
        unsigned _fk = _u ^ (unsigned)(((int)_u >> 31) | 0x80000000);           \
        if (lane == ((SID) & 63)) {                                             \
            rs_lo[(SID) >> 6] = (int)~_cw;                                      \
            rs_hi[(SID) >> 6] = (int)_fk;                                       \
        }                                                                       \
    }

    // 325 unordered pairs, identical FP order to R2: ((total-w[p]) - w[q]) + rect
#pragma unroll
    for (int p = 0; p < 25; ++p) {
#pragma unroll
        for (int q = 0; q < 25; ++q) {
            if (q < p) continue;
            const int p1 = p / 5, p2 = p % 5, q1 = q / 5, q2 = q % 5;
            const int rlo = (p1 > q1 ? p1 : q1);
            const int rmn = (p1 < q1 ? p1 : q1);
            const int rhi = (rmn + 3 > rlo ? rmn + 3 : rlo);
            const int clo = (p2 > q2 ? p2 : q2);
            const int cmn = (p2 < q2 ? p2 : q2);
            const int chi = (cmn + 3 > clo ? cmn + 3 : clo);
            const float rect = ((S[rhi * 8 + chi] - S[rlo * 8 + chi])
                                - S[rhi * 8 + clo]) + S[rlo * 8 + clo];
            const float v = (lt[p] - w_[q]) + rect;
            EMIT(v, tri_off(p) + (q - p));
        }
    }
    // 25 one-mask streams + total stream
#pragma unroll
    for (int i = 0; i < 25; ++i) EMIT(lt[i], 325 + i);
    EMIT(total, 350);
#undef EMIT

    unsigned long long* dst = part + (size_t)(b * NCH + wc) * PSTRIDE + lane;
#pragma unroll
    for (int j = 0; j < 6; ++j)
        dst[j * 64] = ((unsigned long long)(unsigned)rs_hi[j] << 32)
                      | (unsigned)rs_lo[j];
}

// ---------------- Kernel C: merge chunks + final decision ----------------
__global__ __launch_bounds__(128) void kernC(const unsigned long long* __restrict__ part,
                                             int* __restrict__ out) {
    __shared__ unsigned long long mg[352];
    const int b = blockIdx.x;
    const int t = threadIdx.x;
    for (int s = t; s < 352; s += 128) {
        unsigned long long m = 0ull;
#pragma unroll
        for (int wc = 0; wc < NCH; ++wc) {
            unsigned long long v = part[(size_t)(b * NCH + wc) * PSTRIDE + s];
            if (v > m) m = v;
        }
        mg[s] = m;
    }
    __syncthreads();
    if (t < 64) {
        const unsigned predidx = (unsigned)mg[350];
        const int pred = (int)~predidx;
        bool cand = false;
        int p1 = 0;
        if (t < 25) {
            const unsigned p1i = (unsigned)mg[325 + t];
            p1 = (int)~p1i;
            bool ag = true;
            for (int j = 0; j < 25; ++j) {
                const int a = t < j ? t : j;
                const int q = t < j ? j : t;
                ag = ag && ((unsigned)mg[tri_off(a) + (q - a)] == p1i);
            }
            cand = ag && (p1 != pred);
        }
        const unsigned long long mask = __ballot(cand);
        int ans = pred;
        if (mask) ans = __shfl(p1, __ffsll(mask) - 1, 64);
        if (t == 0) out[b] = ans;
    }
}

extern "C" void kernel_launch(void* const* d_in, const int* in_sizes, int n_in,
                              void* d_out, int out_size, void* d_ws, size_t ws_size,
                              hipStream_t stream) {
    const float* x = (const float*)d_in[0];
    int* out = (int*)d_out;

    float* Sws = (float*)d_ws;                                    // 8.192 MB
    unsigned long long* part =
        (unsigned long long*)((char*)d_ws + (size_t)64 * NBC * 4); // 32*16*384*8 = 1.57 MB

    satA<<<NBC / 64, 256, 0, stream>>>(x, Sws);
    kernB<<<256, 128, 0, stream>>>(Sws, part);
    kernC<<<32, 128, 0, stream>>>(part, out);
}